// Round 13
// baseline (58.350 us; speedup 1.0000x reference)
//
#include <hip/hip_runtime.h>

#define N_MENT   10000
#define BATCH    512
#define N_ANTS   50
#define EMB      1024
#define PW_EMB   64
#define IN_F     3136       // 3*EMB + PW_EMB
#define HID      128
#define M_TOT    (BATCH * N_ANTS)   // 25600
#define EPS_VAL  1e-7f
#define SLOPE    0.01f

#define NKT      196        // IN_F/16 k-tiles; chunk c -> [a*4,b*4,sim*4], then pw*4
#define CONV_BLK 196        // 4 tn * 196 tk tiles * 64 lanes / 256
#define MAIN_BLK (M_TOT / 64)   // 400

using f32x4  = __attribute__((ext_vector_type(4)))  float;
using f32x16 = __attribute__((ext_vector_type(16))) float;
using s16x8  = __attribute__((ext_vector_type(8)))  short;
using u16x8  = __attribute__((ext_vector_type(8)))  unsigned short;

__device__ __forceinline__ unsigned short f2bf(float f) {
  unsigned u = __builtin_bit_cast(unsigned, f);
  u += 0x7FFFu + ((u >> 16) & 1u);   // RNE
  return (unsigned short)(u >> 16);
}

// pack 8 f32 -> 8 bf16 (RNE) via v_cvt_pk_bf16_f32 (bit-equal to f2bf; verified R4-R12)
__device__ __forceinline__ u16x8 pack8(float4 lo, float4 hi) {
  union { u16x8 v; unsigned u[4]; } r;
  asm("v_cvt_pk_bf16_f32 %0, %1, %2" : "=v"(r.u[0]) : "v"(lo.x), "v"(lo.y));
  asm("v_cvt_pk_bf16_f32 %0, %1, %2" : "=v"(r.u[1]) : "v"(lo.z), "v"(lo.w));
  asm("v_cvt_pk_bf16_f32 %0, %1, %2" : "=v"(r.u[2]) : "v"(hi.x), "v"(hi.y));
  asm("v_cvt_pk_bf16_f32 %0, %1, %2" : "=v"(r.u[3]) : "v"(hi.z), "v"(hi.w));
  return r.v;
}

__device__ __forceinline__ float4 fmul4(float4 a, float4 b) {
  return make_float4(a.x * b.x, a.y * b.y, a.z * b.z, a.w * b.w);
}

// Chunk barrier that does NOT drain VMEM: make LDS writes visible (lgkmcnt
// only) + raw s_barrier. Global prefetch issued before it stays in flight
// across the chunk boundary (unlike __syncthreads, which waits vmcnt(0)).
__device__ __forceinline__ void chunk_barrier() {
  __builtin_amdgcn_sched_barrier(0);
  asm volatile("s_waitcnt lgkmcnt(0)" ::: "memory");
  __builtin_amdgcn_s_barrier();
  __builtin_amdgcn_sched_barrier(0);
}

// permuted k-tile (16-k tiles) -> original W1 row base.
//   tk in [0,192): chunk c = tk/12, r = tk%12; region = r>>2 (0=a,1=b,2=sim), ks = r&3
//                  orig = region*1024 + c*64 + ks*16
//   tk 192..195 -> pw rows 3072 + (tk-192)*16
__device__ __forceinline__ int tile_orig_k(int tk) {
  if (tk >= 192) return 3072 + (tk - 192) * 16;
  const int c = tk / 12, r = tk % 12;
  return (r >> 2) * 1024 + c * 64 + (r & 3) * 16;
}

// ---- kernel 0: W1 [3136][128] f32 -> w1f in 32x32x16 B-fragment order -------
// w1f element index = ((tn*NKT + tk)*64 + lane)*8 + j
//   lane holds W1[k = orig_k(tk) + (lane>>5)*8 + j][n = tn*32 + (lane&31)]
__global__ __launch_bounds__(256) void k_convert(const float* __restrict__ w1,
                                                 unsigned short* __restrict__ w1f) {
  const int id   = blockIdx.x * 256 + threadIdx.x;   // 0..50175
  const int lane = id & 63;
  const int tile = id >> 6;                          // 0..783 = tn*196 + tk
  const int tk   = tile % NKT, tn = tile / NKT;
  const int n    = tn * 32 + (lane & 31);
  const int k    = tile_orig_k(tk) + (lane >> 5) * 8;
  u16x8 o;
  #pragma unroll
  for (int j = 0; j < 8; ++j) o[j] = f2bf(w1[(size_t)(k + j) * HID + n]);
  *(u16x8*)(w1f + (size_t)id * 8) = o;
}

// ---- kernel 1: fused GEMM, K=3136, BM=64, 32x32x16 MFMA, swizzled LDS,
//      raw-barrier pipeline (VMEM stays in flight across chunk boundaries) ----
__global__ __launch_bounds__(512, 4) void k_main(
    const float* __restrict__ all_m, const float* __restrict__ men,
    const float* __restrict__ pw, const int* __restrict__ topi,
    const float* __restrict__ rough, const unsigned short* __restrict__ w1f,
    const float* __restrict__ b1, const float* __restrict__ wout,
    const float* __restrict__ bout, float* __restrict__ out) {
  __shared__ __align__(16) unsigned short Xs[2][3][64 * 64];
  __shared__ float red[4][64];

  const int t  = threadIdx.x;
  const int m0 = blockIdx.x * 64;

  // staging identity: row sr (0..63), 16B col unit sq (0..7)
  const int sr = t >> 3, sq = t & 7;
  const int m  = m0 + sr;
  const int bb = m / N_ANTS;
  const int bidx = topi[m];
  const float* pA = men   + (size_t)bb   * EMB    + sq * 8;
  const float* pB = all_m + (size_t)bidx * EMB    + sq * 8;
  const float* pP = pw    + (size_t)m    * PW_EMB + sq * 8;
  // swizzled write index (in shorts): 16B unit sq XOR'd with row&7
  const int widx = sr * 64 + (((sq * 16) ^ ((sr & 7) << 4)) >> 1);

  // compute identity: wave wid -> tn = wid&3, mt = wid>>2
  const int lane = t & 63, wid = t >> 6;
  const int rowL = lane & 31, lh = lane >> 5;
  const int tn = wid & 3, mt = wid >> 2;
  const unsigned short* wf = w1f + (size_t)tn * NKT * 512 + lane * 8;

  // swizzled read indices (in shorts) for ks = 0..3 of this wave's rows
  const int grow = mt * 32 + rowL;
  int ridx[4];
  #pragma unroll
  for (int ks = 0; ks < 4; ++ks)
    ridx[ks] = grow * 64 + ((((ks * 32 + lh * 16)) ^ ((grow & 7) << 4)) >> 1);

  f32x16 acc = {};

  float4 av0 = ((const float4*)pA)[0], av1 = ((const float4*)pA)[1];
  float4 bv0 = ((const float4*)pB)[0], bv1 = ((const float4*)pB)[1];

  int buf = 0;
  for (int c = 0; c < 16; ++c) {
    // (1) THIS chunk's 12 W fragments -- issued FIRST (oldest VMEM), so the
    //     pre-MFMA vmcnt wait for them leaves the younger a/b prefetch in
    //     flight across the barrier.
    s16x8 wr[12];
    #pragma unroll
    for (int j = 0; j < 12; ++j)
      wr[j] = *(const s16x8*)(wf + (size_t)(c * 12 + j) * 512);

    // (2) stage three tiles: 0 = a, 1 = b, 2 = a*b (one 16B swizzled write each)
    *(u16x8*)&Xs[buf][0][widx] = pack8(av0, av1);
    *(u16x8*)&Xs[buf][1][widx] = pack8(bv0, bv1);
    *(u16x8*)&Xs[buf][2][widx] = pack8(fmul4(av0, bv0), fmul4(av1, bv1));

    // (3) prefetch next chunk's rows (youngest VMEM; stays in flight through
    //     the raw barrier, completing under the whole next-chunk window)
    if (c < 15) {
      const float* qA = pA + (c + 1) * 64;
      const float* qB = pB + (c + 1) * 64;
      av0 = ((const float4*)qA)[0]; av1 = ((const float4*)qA)[1];
      bv0 = ((const float4*)qB)[0]; bv1 = ((const float4*)qB)[1];
    } else {
      av0 = ((const float4*)pP)[0]; av1 = ((const float4*)pP)[1];
    }

    // (4) LDS-visibility barrier only -- no vmcnt drain
    chunk_barrier();

    // (5) MFMA phase
    #pragma unroll
    for (int reg = 0; reg < 3; ++reg)
      #pragma unroll
      for (int ks = 0; ks < 4; ++ks) {
        s16x8 x = *(const s16x8*)&Xs[buf][reg][ridx[ks]];
        acc = __builtin_amdgcn_mfma_f32_32x32x16_bf16(x, wr[reg * 4 + ks], acc, 0, 0, 0);
      }
    buf ^= 1;
  }

  // pw chunk: av0/av1 hold pw values; k-tiles 192..195
  {
    s16x8 wr[4];
    #pragma unroll
    for (int ks = 0; ks < 4; ++ks)
      wr[ks] = *(const s16x8*)(wf + (size_t)(192 + ks) * 512);
    *(u16x8*)&Xs[buf][0][widx] = pack8(av0, av1);
    chunk_barrier();
    #pragma unroll
    for (int ks = 0; ks < 4; ++ks) {
      s16x8 x = *(const s16x8*)&Xs[buf][0][ridx[ks]];
      acc = __builtin_amdgcn_mfma_f32_32x32x16_bf16(x, wr[ks], acc, 0, 0, 0);
    }
  }

  // epilogue: lane holds C[m = mt*32 + (e&3)+8*(e>>2)+4*lh][n = tn*32 + rowL]
  const int n0 = tn * 32 + rowL;
  const float bias = b1[n0], w_o = wout[n0];
  #pragma unroll
  for (int e = 0; e < 16; ++e) {
    float h = acc[e] + bias;
    h = h > 0.f ? h : SLOPE * h;
    float ss = h * w_o;
    ss += __shfl_xor(ss, 1);
    ss += __shfl_xor(ss, 2);
    ss += __shfl_xor(ss, 4);
    ss += __shfl_xor(ss, 8);
    ss += __shfl_xor(ss, 16);
    if (rowL == 0) {
      const int rl = (e & 3) + 8 * (e >> 2) + 4 * lh;
      red[tn][mt * 32 + rl] = ss;
    }
  }
  __syncthreads();
  if (t < 64) {
    const int gm = m0 + t;
    const float v = red[0][t] + red[1][t] + red[2][t] + red[3][t];
    const int gb = gm / N_ANTS;
    const int ga = gm - gb * N_ANTS;
    out[(size_t)gb * (N_ANTS + 1) + 1 + ga] = rough[gm] + v + bout[0];
  }
  if (t == 0) {   // EPSILON dummy column (duplicate same-value writes benign)
    for (int g = m0 / N_ANTS; g <= (m0 + 63) / N_ANTS; ++g)
      out[(size_t)g * (N_ANTS + 1)] = EPS_VAL;
  }
}

// ---- fallback (exact f32, used only if workspace too small) -----------------
__global__ void k_eps(float* __restrict__ out) {
  out[(size_t)threadIdx.x * (N_ANTS + 1)] = EPS_VAL;
}

__global__ __launch_bounds__(128) void k_fb(const float* __restrict__ all_m,
                                            const float* __restrict__ men,
                                            const float* __restrict__ pw,
                                            const int*   __restrict__ topi,
                                            const float* __restrict__ rough,
                                            const float* __restrict__ w1,
                                            const float* __restrict__ b1,
                                            const float* __restrict__ wout,
                                            const float* __restrict__ bout,
                                            float* __restrict__ out) {
  __shared__ float xs[IN_F];
  __shared__ float hred[HID];
  const int pair = blockIdx.x;
  const int t = threadIdx.x;
  const int bb = pair / N_ANTS;
  const int idx = topi[pair];
  const float* pA = men + (size_t)bb * EMB;
  const float* pB = all_m + (size_t)idx * EMB;
  for (int k = t; k < EMB; k += 128) {
    float a = pA[k], b = pB[k];
    xs[k] = a; xs[EMB + k] = b; xs[2 * EMB + k] = a * b;
  }
  if (t < PW_EMB) xs[3 * EMB + t] = pw[(size_t)pair * PW_EMB + t];
  __syncthreads();
  float acc = 0.f;
  for (int k = 0; k < IN_F; ++k) acc = fmaf(xs[k], w1[(size_t)k * HID + t], acc);
  acc += b1[t];
  acc = acc > 0.f ? acc : SLOPE * acc;
  hred[t] = acc * wout[t];
  __syncthreads();
  for (int off = 64; off > 0; off >>= 1) {
    if (t < off) hred[t] += hred[t + off];
    __syncthreads();
  }
  if (t == 0)
    out[(size_t)bb * (N_ANTS + 1) + 1 + (pair - bb * N_ANTS)] = rough[pair] + hred[0] + bout[0];
}

extern "C" void kernel_launch(void* const* d_in, const int* in_sizes, int n_in,
                              void* d_out, int out_size, void* d_ws, size_t ws_size,
                              hipStream_t stream) {
  const float* all_m = (const float*)d_in[0];
  const float* men   = (const float*)d_in[1];
  const float* pw    = (const float*)d_in[2];
  const int*   topi  = (const int*)  d_in[3];
  const float* rough = (const float*)d_in[4];
  const float* w1    = (const float*)d_in[5];
  const float* b1    = (const float*)d_in[6];
  const float* wout  = (const float*)d_in[7];
  const float* bout  = (const float*)d_in[8];
  float* out = (float*)d_out;

  const size_t W1F_BYTES = (size_t)HID * IN_F * sizeof(unsigned short);   // 802816

  if (ws_size >= W1F_BYTES) {
    unsigned short* w1f = (unsigned short*)d_ws;
    k_convert<<<CONV_BLK, 256, 0, stream>>>(w1, w1f);
    k_main<<<MAIN_BLK, 512, 0, stream>>>(all_m, men, pw, topi, rough, w1f,
                                         b1, wout, bout, out);
  } else {
    k_eps<<<1, BATCH, 0, stream>>>(out);
    k_fb<<<M_TOT, 128, 0, stream>>>(all_m, men, pw, topi, rough, w1, b1, wout, bout, out);
  }
}

// Round 14
// 48.888 us; speedup vs baseline: 1.1935x; 1.1935x over previous
//
#include <hip/hip_runtime.h>

#define N_MENT   10000
#define BATCH    512
#define N_ANTS   50
#define EMB      1024
#define PW_EMB   64
#define IN_F     3136       // 3*EMB + PW_EMB
#define HID      128
#define M_TOT    (BATCH * N_ANTS)   // 25600
#define EPS_VAL  1e-7f
#define SLOPE    0.01f

#define NKT      98         // IN_F/32 k-tiles, permuted: chunk c -> [a,a,b,b,s,s], then pw,pw
#define CONV_BLK 196        // 8 tn * 98 tk * 64 lanes / 256
#define MAIN_BLK BATCH      // 512 blocks, one batch-row each (50 pairs + 14 pad)

using f32x4 = __attribute__((ext_vector_type(4))) float;
using s16x8 = __attribute__((ext_vector_type(8))) short;
using u16x4 = __attribute__((ext_vector_type(4))) unsigned short;
using u16x8 = __attribute__((ext_vector_type(8))) unsigned short;

__device__ __forceinline__ unsigned short f2bf(float f) {
  unsigned u = __builtin_bit_cast(unsigned, f);
  u += 0x7FFFu + ((u >> 16) & 1u);   // RNE
  return (unsigned short)(u >> 16);
}

// pack 4 f32 -> 4 bf16 (RNE) via v_cvt_pk_bf16_f32 (bit-equal to f2bf; verified R4-R13)
__device__ __forceinline__ u16x4 pack4(float4 v) {
  union { u16x4 o; unsigned u[2]; } r;
  asm("v_cvt_pk_bf16_f32 %0, %1, %2" : "=v"(r.u[0]) : "v"(v.x), "v"(v.y));
  asm("v_cvt_pk_bf16_f32 %0, %1, %2" : "=v"(r.u[1]) : "v"(v.z), "v"(v.w));
  return r.o;
}

__device__ __forceinline__ float4 fmul4(float4 a, float4 b) {
  return make_float4(a.x * b.x, a.y * b.y, a.z * b.z, a.w * b.w);
}

// permuted k-tile -> original W1 row base (R10 layout).
//   tk in [0,96): chunk c = tk/6, r = tk%6; region = r>>1 (0=a,1=b,2=sim), ks = r&1
//                 orig = region*1024 + c*64 + ks*32
//   tk 96,97   -> pw rows 3072 + (tk-96)*32
__device__ __forceinline__ int tile_orig_k(int tk) {
  if (tk >= 96) return 3072 + (tk - 96) * 32;
  const int c = tk / 6, r = tk % 6;
  return (r >> 1) * 1024 + c * 64 + (r & 1) * 32;
}

// ---- kernel 0: W1 [3136][128] f32 -> w1f in MFMA B-fragment-linear order ----
// w1f element index = ((tn*NKT + tk)*64 + lane)*8 + j
//   lane = ln + lg*16 holds W1[k = orig_k(tk) + lg*8 + j][n = tn*16 + ln]
__global__ __launch_bounds__(256) void k_convert(const float* __restrict__ w1,
                                                 unsigned short* __restrict__ w1f) {
  const int id   = blockIdx.x * 256 + threadIdx.x;   // 0..50175
  const int lane = id & 63;
  const int tile = id >> 6;                          // 0..783 = tn*98 + tk
  const int tk   = tile % NKT, tn = tile / NKT;
  const int n    = tn * 16 + (lane & 15);
  const int k    = tile_orig_k(tk) + (lane >> 4) * 8;
  u16x8 o;
  #pragma unroll
  for (int j = 0; j < 8; ++j) o[j] = f2bf(w1[(size_t)(k + j) * HID + n]);
  *(u16x8*)(w1f + (size_t)id * 8) = o;
}

// ---- kernel 1: fused GEMM, K=3136, one batch-row per block (BM=50 pad 64) ---
// Exact R10 schedule (best measured: one barrier/chunk, depth-1 W prefetch,
// wave owns one 16-col n-tile x all 4 m-tiles). Grid 512 = uniform 2
// blocks/CU (R10's 400-block grid left 112 CUs half-idle). All staging rows
// share one a-row (L1-hot); only 50 unique b-gathers per block.
__global__ __launch_bounds__(512) void k_main(
    const float* __restrict__ all_m, const float* __restrict__ men,
    const float* __restrict__ pw, const int* __restrict__ topi,
    const float* __restrict__ rough, const unsigned short* __restrict__ w1f,
    const float* __restrict__ b1, const float* __restrict__ wout,
    const float* __restrict__ bout, float* __restrict__ out) {
  __shared__ __align__(16) unsigned short Xs[2][3][64 * 72];
  __shared__ float red[8][64];

  const int t   = threadIdx.x;
  const int bid = blockIdx.x;            // batch row
  const int mbase = bid * N_ANTS;

  // staging identity: row sr (0..63, clamped to 49), 8-float col group sq (0..7)
  const int sr = t >> 3, sq = t & 7;
  const int r  = sr < N_ANTS ? sr : N_ANTS - 1;
  const int m  = mbase + r;
  const int bidx = topi[m];
  const float* pA = men   + (size_t)bid  * EMB    + sq * 8;   // same row for all
  const float* pB = all_m + (size_t)bidx * EMB    + sq * 8;
  const float* pP = pw    + (size_t)m    * PW_EMB + sq * 8;

  // compute identity: wave wid (0..7) owns n-tile wid
  const int lane = t & 63, wid = t >> 6;
  const int ln = lane & 15, lg = lane >> 4;
  const unsigned short* wf = w1f + (size_t)wid * NKT * 512 + lane * 8;

  f32x4 acc[4] = {};   // acc[mt]: rows mbase-tile + mt*16 .. +15

  float4 av0 = ((const float4*)pA)[0], av1 = ((const float4*)pA)[1];
  float4 bv0 = ((const float4*)pB)[0], bv1 = ((const float4*)pB)[1];

  // W fragments for chunk 0 (k-tiles 0..5)
  s16x8 wcur[6], wnext[6];
  #pragma unroll
  for (int j = 0; j < 6; ++j)
    wcur[j] = *(const s16x8*)(wf + (size_t)j * 512);

  int buf = 0;
  for (int c = 0; c < 16; ++c) {
    // stage three tiles: 0 = a, 1 = b, 2 = a*b   (16B per thread per tile)
    *(u16x4*)&Xs[buf][0][sr * 72 + sq * 8]     = pack4(av0);
    *(u16x4*)&Xs[buf][0][sr * 72 + sq * 8 + 4] = pack4(av1);
    *(u16x4*)&Xs[buf][1][sr * 72 + sq * 8]     = pack4(bv0);
    *(u16x4*)&Xs[buf][1][sr * 72 + sq * 8 + 4] = pack4(bv1);
    *(u16x4*)&Xs[buf][2][sr * 72 + sq * 8]     = pack4(fmul4(av0, bv0));
    *(u16x4*)&Xs[buf][2][sr * 72 + sq * 8 + 4] = pack4(fmul4(av1, bv1));

    // depth-1 prefetch of next chunk's rows (pw at the end; bv unused then)
    if (c < 15) {
      const float* qA = pA + (c + 1) * 64;
      const float* qB = pB + (c + 1) * 64;
      av0 = ((const float4*)qA)[0]; av1 = ((const float4*)qA)[1];
      bv0 = ((const float4*)qB)[0]; bv1 = ((const float4*)qB)[1];
    } else {
      av0 = ((const float4*)pP)[0]; av1 = ((const float4*)pP)[1];
    }

    // depth-1 prefetch of NEXT chunk's W fragments (R3/R10-proven pattern)
    #pragma unroll
    for (int j = 0; j < 6; ++j) {
      const int tkn = (c < 15) ? (c + 1) * 6 + j : (j < 2 ? 96 + j : 97);
      wnext[j] = *(const s16x8*)(wf + (size_t)tkn * 512);
    }

    __syncthreads();
    #pragma unroll
    for (int j = 0; j < 6; ++j) {
      const int reg = j >> 1, ks = j & 1;
      #pragma unroll
      for (int mt = 0; mt < 4; ++mt) {
        s16x8 x = *(const s16x8*)&Xs[buf][reg][(mt * 16 + ln) * 72 + ks * 32 + lg * 8];
        acc[mt] = __builtin_amdgcn_mfma_f32_16x16x32_bf16(x, wcur[j], acc[mt], 0, 0, 0);
      }
    }
    #pragma unroll
    for (int j = 0; j < 6; ++j) wcur[j] = wnext[j];
    buf ^= 1;
  }

  // pw chunk: av0/av1 hold pw values; k-tiles 96,97 are wcur[0],wcur[1]
  {
    *(u16x4*)&Xs[buf][0][sr * 72 + sq * 8]     = pack4(av0);
    *(u16x4*)&Xs[buf][0][sr * 72 + sq * 8 + 4] = pack4(av1);
    __syncthreads();
    #pragma unroll
    for (int ks = 0; ks < 2; ++ks)
      #pragma unroll
      for (int mt = 0; mt < 4; ++mt) {
        s16x8 x = *(const s16x8*)&Xs[buf][0][(mt * 16 + ln) * 72 + ks * 32 + lg * 8];
        acc[mt] = __builtin_amdgcn_mfma_f32_16x16x32_bf16(x, wcur[ks], acc[mt], 0, 0, 0);
      }
  }

  // epilogue: lane holds C[m = mt*16 + lg*4 + e][n = wid*16 + ln]
  const int n0 = wid * 16 + ln;
  const float bias = b1[n0], w_o = wout[n0];
  #pragma unroll
  for (int mt = 0; mt < 4; ++mt)
    #pragma unroll
    for (int e = 0; e < 4; ++e) {
      float h = acc[mt][e] + bias;
      h = h > 0.f ? h : SLOPE * h;
      float ss = h * w_o;
      ss += __shfl_xor(ss, 1);
      ss += __shfl_xor(ss, 2);
      ss += __shfl_xor(ss, 4);
      ss += __shfl_xor(ss, 8);
      if (ln == 0) red[wid][mt * 16 + lg * 4 + e] = ss;
    }
  __syncthreads();
  if (t < N_ANTS) {
    const int gm = mbase + t;
    float v = red[0][t];
    #pragma unroll
    for (int w = 1; w < 8; ++w) v += red[w][t];
    out[(size_t)bid * (N_ANTS + 1) + 1 + t] = rough[gm] + v + bout[0];
  }
  if (t == 0) out[(size_t)bid * (N_ANTS + 1)] = EPS_VAL;   // dummy column
}

// ---- fallback (exact f32, used only if workspace too small) -----------------
__global__ void k_eps(float* __restrict__ out) {
  out[(size_t)threadIdx.x * (N_ANTS + 1)] = EPS_VAL;
}

__global__ __launch_bounds__(128) void k_fb(const float* __restrict__ all_m,
                                            const float* __restrict__ men,
                                            const float* __restrict__ pw,
                                            const int*   __restrict__ topi,
                                            const float* __restrict__ rough,
                                            const float* __restrict__ w1,
                                            const float* __restrict__ b1,
                                            const float* __restrict__ wout,
                                            const float* __restrict__ bout,
                                            float* __restrict__ out) {
  __shared__ float xs[IN_F];
  __shared__ float hred[HID];
  const int pair = blockIdx.x;
  const int t = threadIdx.x;
  const int bb = pair / N_ANTS;
  const int idx = topi[pair];
  const float* pA = men + (size_t)bb * EMB;
  const float* pB = all_m + (size_t)idx * EMB;
  for (int k = t; k < EMB; k += 128) {
    float a = pA[k], b = pB[k];
    xs[k] = a; xs[EMB + k] = b; xs[2 * EMB + k] = a * b;
  }
  if (t < PW_EMB) xs[3 * EMB + t] = pw[(size_t)pair * PW_EMB + t];
  __syncthreads();
  float acc = 0.f;
  for (int k = 0; k < IN_F; ++k) acc = fmaf(xs[k], w1[(size_t)k * HID + t], acc);
  acc += b1[t];
  acc = acc > 0.f ? acc : SLOPE * acc;
  hred[t] = acc * wout[t];
  __syncthreads();
  for (int off = 64; off > 0; off >>= 1) {
    if (t < off) hred[t] += hred[t + off];
    __syncthreads();
  }
  if (t == 0)
    out[(size_t)bb * (N_ANTS + 1) + 1 + (pair - bb * N_ANTS)] = rough[pair] + hred[0] + bout[0];
}

extern "C" void kernel_launch(void* const* d_in, const int* in_sizes, int n_in,
                              void* d_out, int out_size, void* d_ws, size_t ws_size,
                              hipStream_t stream) {
  const float* all_m = (const float*)d_in[0];
  const float* men   = (const float*)d_in[1];
  const float* pw    = (const float*)d_in[2];
  const int*   topi  = (const int*)  d_in[3];
  const float* rough = (const float*)d_in[4];
  const float* w1    = (const float*)d_in[5];
  const float* b1    = (const float*)d_in[6];
  const float* wout  = (const float*)d_in[7];
  const float* bout  = (const float*)d_in[8];
  float* out = (float*)d_out;

  const size_t W1F_BYTES = (size_t)HID * IN_F * sizeof(unsigned short);   // 802816

  if (ws_size >= W1F_BYTES) {
    unsigned short* w1f = (unsigned short*)d_ws;
    k_convert<<<CONV_BLK, 256, 0, stream>>>(w1, w1f);
    k_main<<<MAIN_BLK, 512, 0, stream>>>(all_m, men, pw, topi, rough, w1f,
                                         b1, wout, bout, out);
  } else {
    k_eps<<<1, BATCH, 0, stream>>>(out);
    k_fb<<<M_TOT, 128, 0, stream>>>(all_m, men, pw, topi, rough, w1, b1, wout, bout, out);
  }
}

// Round 15
// 44.494 us; speedup vs baseline: 1.3114x; 1.0987x over previous
//
#include <hip/hip_runtime.h>

#define N_MENT   10000
#define BATCH    512
#define N_ANTS   50
#define EMB      1024
#define PW_EMB   64
#define IN_F     3136       // 3*EMB + PW_EMB
#define HID      128
#define M_TOT    (BATCH * N_ANTS)   // 25600
#define EPS_VAL  1e-7f
#define SLOPE    0.01f

#define NKT      98         // IN_F/32 k-tiles, permuted: chunk c -> [a,a,b,b,s,s], then pw,pw
#define CONV_BLK 196        // 8 tn * 98 tk * 64 lanes / 256
#define MAIN_BLK BATCH      // 512 blocks, one batch-row each (50 pairs + 14 pad)

using f32x4 = __attribute__((ext_vector_type(4))) float;
using s16x8 = __attribute__((ext_vector_type(8))) short;
using u16x8 = __attribute__((ext_vector_type(8))) unsigned short;

__device__ __forceinline__ unsigned short f2bf(float f) {
  unsigned u = __builtin_bit_cast(unsigned, f);
  u += 0x7FFFu + ((u >> 16) & 1u);   // RNE
  return (unsigned short)(u >> 16);
}

// pack 8 f32 -> 8 bf16 (RNE) via v_cvt_pk_bf16_f32 (bit-equal to f2bf; verified R4-R14)
__device__ __forceinline__ u16x8 pack8(float4 lo, float4 hi) {
  union { u16x8 v; unsigned u[4]; } r;
  asm("v_cvt_pk_bf16_f32 %0, %1, %2" : "=v"(r.u[0]) : "v"(lo.x), "v"(lo.y));
  asm("v_cvt_pk_bf16_f32 %0, %1, %2" : "=v"(r.u[1]) : "v"(lo.z), "v"(lo.w));
  asm("v_cvt_pk_bf16_f32 %0, %1, %2" : "=v"(r.u[2]) : "v"(hi.x), "v"(hi.y));
  asm("v_cvt_pk_bf16_f32 %0, %1, %2" : "=v"(r.u[3]) : "v"(hi.z), "v"(hi.w));
  return r.v;
}

__device__ __forceinline__ float4 fmul4(float4 a, float4 b) {
  return make_float4(a.x * b.x, a.y * b.y, a.z * b.z, a.w * b.w);
}

// permuted k-tile -> original W1 row base (R10 layout).
//   tk in [0,96): chunk c = tk/6, r = tk%6; region = r>>1 (0=a,1=b,2=sim), ks = r&1
//                 orig = region*1024 + c*64 + ks*32
//   tk 96,97   -> pw rows 3072 + (tk-96)*32
__device__ __forceinline__ int tile_orig_k(int tk) {
  if (tk >= 96) return 3072 + (tk - 96) * 32;
  const int c = tk / 6, r = tk % 6;
  return (r >> 1) * 1024 + c * 64 + (r & 1) * 32;
}

// ---- kernel 0: W1 [3136][128] f32 -> w1f in MFMA B-fragment-linear order ----
// w1f element index = ((tn*NKT + tk)*64 + lane)*8 + j
//   lane = ln + lg*16 holds W1[k = orig_k(tk) + lg*8 + j][n = tn*16 + ln]
__global__ __launch_bounds__(256) void k_convert(const float* __restrict__ w1,
                                                 unsigned short* __restrict__ w1f) {
  const int id   = blockIdx.x * 256 + threadIdx.x;   // 0..50175
  const int lane = id & 63;
  const int tile = id >> 6;                          // 0..783 = tn*98 + tk
  const int tk   = tile % NKT, tn = tile / NKT;
  const int n    = tn * 16 + (lane & 15);
  const int k    = tile_orig_k(tk) + (lane >> 4) * 8;
  u16x8 o;
  #pragma unroll
  for (int j = 0; j < 8; ++j) o[j] = f2bf(w1[(size_t)(k + j) * HID + n]);
  *(u16x8*)(w1f + (size_t)id * 8) = o;
}

// ---- kernel 1: fused GEMM, K=3136, one batch-row per block, swizzled LDS ----
// R14 schedule (best measured) with T2 XOR-swizzle on the X tiles:
// [64 rows][64 shorts = 128B], byte_off ^= ((row&7)<<4) on BOTH sides.
// Derivation: writes -- each row's 8 16B-units cover all 32 banks (8/bank =
// HW minimum, conflict-free). reads -- 8 lanes per bank-quad = minimum.
__global__ __launch_bounds__(512) void k_main(
    const float* __restrict__ all_m, const float* __restrict__ men,
    const float* __restrict__ pw, const int* __restrict__ topi,
    const float* __restrict__ rough, const unsigned short* __restrict__ w1f,
    const float* __restrict__ b1, const float* __restrict__ wout,
    const float* __restrict__ bout, float* __restrict__ out) {
  __shared__ __align__(16) unsigned short Xs[2][3][64 * 64];
  __shared__ float red[8][64];

  const int t   = threadIdx.x;
  const int bid = blockIdx.x;            // batch row
  const int mbase = bid * N_ANTS;

  // staging identity: row sr (0..63, clamped to 49), 8-float col group sq (0..7)
  const int sr = t >> 3, sq = t & 7;
  const int r  = sr < N_ANTS ? sr : N_ANTS - 1;
  const int m  = mbase + r;
  const int bidx = topi[m];
  const float* pA = men   + (size_t)bid  * EMB    + sq * 8;   // same row for all
  const float* pB = all_m + (size_t)bidx * EMB    + sq * 8;
  const float* pP = pw    + (size_t)m    * PW_EMB + sq * 8;
  // swizzled write index (in shorts): 16B unit sq, byte ^= (sr&7)<<4
  const int widx = sr * 64 + (((sq * 16) ^ ((sr & 7) << 4)) >> 1);

  // compute identity: wave wid (0..7) owns n-tile wid
  const int lane = t & 63, wid = t >> 6;
  const int ln = lane & 15, lg = lane >> 4;
  const unsigned short* wf = w1f + (size_t)wid * NKT * 512 + lane * 8;

  // swizzled read indices (in shorts): row R = mt*16+ln, byte col ks*64+lg*16
  int ridx[2][4];
  #pragma unroll
  for (int ks = 0; ks < 2; ++ks)
    #pragma unroll
    for (int mt = 0; mt < 4; ++mt) {
      const int R = mt * 16 + ln;
      ridx[ks][mt] = R * 64 + (((ks * 64 + lg * 16) ^ ((R & 7) << 4)) >> 1);
    }

  f32x4 acc[4] = {};   // acc[mt]: rows mbase-tile + mt*16 .. +15

  float4 av0 = ((const float4*)pA)[0], av1 = ((const float4*)pA)[1];
  float4 bv0 = ((const float4*)pB)[0], bv1 = ((const float4*)pB)[1];

  // W fragments for chunk 0 (k-tiles 0..5)
  s16x8 wcur[6], wnext[6];
  #pragma unroll
  for (int j = 0; j < 6; ++j)
    wcur[j] = *(const s16x8*)(wf + (size_t)j * 512);

  int buf = 0;
  for (int c = 0; c < 16; ++c) {
    // stage three tiles: 0 = a, 1 = b, 2 = a*b  (one 16B swizzled write each)
    *(u16x8*)&Xs[buf][0][widx] = pack8(av0, av1);
    *(u16x8*)&Xs[buf][1][widx] = pack8(bv0, bv1);
    *(u16x8*)&Xs[buf][2][widx] = pack8(fmul4(av0, bv0), fmul4(av1, bv1));

    // depth-1 prefetch of next chunk's rows (pw at the end; bv unused then)
    if (c < 15) {
      const float* qA = pA + (c + 1) * 64;
      const float* qB = pB + (c + 1) * 64;
      av0 = ((const float4*)qA)[0]; av1 = ((const float4*)qA)[1];
      bv0 = ((const float4*)qB)[0]; bv1 = ((const float4*)qB)[1];
    } else {
      av0 = ((const float4*)pP)[0]; av1 = ((const float4*)pP)[1];
    }

    // depth-1 prefetch of NEXT chunk's W fragments (R3/R10-proven pattern)
    #pragma unroll
    for (int j = 0; j < 6; ++j) {
      const int tkn = (c < 15) ? (c + 1) * 6 + j : (j < 2 ? 96 + j : 97);
      wnext[j] = *(const s16x8*)(wf + (size_t)tkn * 512);
    }

    __syncthreads();
    #pragma unroll
    for (int j = 0; j < 6; ++j) {
      const int reg = j >> 1, ks = j & 1;
      #pragma unroll
      for (int mt = 0; mt < 4; ++mt) {
        s16x8 x = *(const s16x8*)&Xs[buf][reg][ridx[ks][mt]];
        acc[mt] = __builtin_amdgcn_mfma_f32_16x16x32_bf16(x, wcur[j], acc[mt], 0, 0, 0);
      }
    }
    #pragma unroll
    for (int j = 0; j < 6; ++j) wcur[j] = wnext[j];
    buf ^= 1;
  }

  // pw chunk: av0/av1 hold pw values; k-tiles 96,97 are wcur[0],wcur[1]
  {
    *(u16x8*)&Xs[buf][0][widx] = pack8(av0, av1);
    __syncthreads();
    #pragma unroll
    for (int ks = 0; ks < 2; ++ks)
      #pragma unroll
      for (int mt = 0; mt < 4; ++mt) {
        s16x8 x = *(const s16x8*)&Xs[buf][0][ridx[ks][mt]];
        acc[mt] = __builtin_amdgcn_mfma_f32_16x16x32_bf16(x, wcur[ks], acc[mt], 0, 0, 0);
      }
  }

  // epilogue: lane holds C[m = mt*16 + lg*4 + e][n = wid*16 + ln]
  const int n0 = wid * 16 + ln;
  const float bias = b1[n0], w_o = wout[n0];
  #pragma unroll
  for (int mt = 0; mt < 4; ++mt)
    #pragma unroll
    for (int e = 0; e < 4; ++e) {
      float h = acc[mt][e] + bias;
      h = h > 0.f ? h : SLOPE * h;
      float ss = h * w_o;
      ss += __shfl_xor(ss, 1);
      ss += __shfl_xor(ss, 2);
      ss += __shfl_xor(ss, 4);
      ss += __shfl_xor(ss, 8);
      if (ln == 0) red[wid][mt * 16 + lg * 4 + e] = ss;
    }
  __syncthreads();
  if (t < N_ANTS) {
    const int gm = mbase + t;
    float v = red[0][t];
    #pragma unroll
    for (int w = 1; w < 8; ++w) v += red[w][t];
    out[(size_t)bid * (N_ANTS + 1) + 1 + t] = rough[gm] + v + bout[0];
  }
  if (t == 0) out[(size_t)bid * (N_ANTS + 1)] = EPS_VAL;   // dummy column
}

// ---- fallback (exact f32, used only if workspace too small) -----------------
__global__ void k_eps(float* __restrict__ out) {
  out[(size_t)threadIdx.x * (N_ANTS + 1)] = EPS_VAL;
}

__global__ __launch_bounds__(128) void k_fb(const float* __restrict__ all_m,
                                            const float* __restrict__ men,
                                            const float* __restrict__ pw,
                                            const int*   __restrict__ topi,
                                            const float* __restrict__ rough,
                                            const float* __restrict__ w1,
                                            const float* __restrict__ b1,
                                            const float* __restrict__ wout,
                                            const float* __restrict__ bout,
                                            float* __restrict__ out) {
  __shared__ float xs[IN_F];
  __shared__ float hred[HID];
  const int pair = blockIdx.x;
  const int t = threadIdx.x;
  const int bb = pair / N_ANTS;
  const int idx = topi[pair];
  const float* pA = men + (size_t)bb * EMB;
  const float* pB = all_m + (size_t)idx * EMB;
  for (int k = t; k < EMB; k += 128) {
    float a = pA[k], b = pB[k];
    xs[k] = a; xs[EMB + k] = b; xs[2 * EMB + k] = a * b;
  }
  if (t < PW_EMB) xs[3 * EMB + t] = pw[(size_t)pair * PW_EMB + t];
  __syncthreads();
  float acc = 0.f;
  for (int k = 0; k < IN_F; ++k) acc = fmaf(xs[k], w1[(size_t)k * HID + t], acc);
  acc += b1[t];
  acc = acc > 0.f ? acc : SLOPE * acc;
  hred[t] = acc * wout[t];
  __syncthreads();
  for (int off = 64; off > 0; off >>= 1) {
    if (t < off) hred[t] += hred[t + off];
    __syncthreads();
  }
  if (t == 0)
    out[(size_t)bb * (N_ANTS + 1) + 1 + (pair - bb * N_ANTS)] = rough[pair] + hred[0] + bout[0];
}

extern "C" void kernel_launch(void* const* d_in, const int* in_sizes, int n_in,
                              void* d_out, int out_size, void* d_ws, size_t ws_size,
                              hipStream_t stream) {
  const float* all_m = (const float*)d_in[0];
  const float* men   = (const float*)d_in[1];
  const float* pw    = (const float*)d_in[2];
  const int*   topi  = (const int*)  d_in[3];
  const float* rough = (const float*)d_in[4];
  const float* w1    = (const float*)d_in[5];
  const float* b1    = (const float*)d_in[6];
  const float* wout  = (const float*)d_in[7];
  const float* bout  = (const float*)d_in[8];
  float* out = (float*)d_out;

  const size_t W1F_BYTES = (size_t)HID * IN_F * sizeof(unsigned short);   // 802816

  if (ws_size >= W1F_BYTES) {
    unsigned short* w1f = (unsigned short*)d_ws;
    k_convert<<<CONV_BLK, 256, 0, stream>>>(w1, w1f);
    k_main<<<MAIN_BLK, 512, 0, stream>>>(all_m, men, pw, topi, rough, w1f,
                                         b1, wout, bout, out);
  } else {
    k_eps<<<1, BATCH, 0, stream>>>(out);
    k_fb<<<M_TOT, 128, 0, stream>>>(all_m, men, pw, topi, rough, w1, b1, wout, bout, out);
  }
}